// Round 11
// baseline (372.752 us; speedup 1.0000x reference)
//
#include <hip/hip_runtime.h>
#include <hip/hip_bf16.h>

#define SEQ 4224
#define KSPLIT 11
#define KITERS 6
typedef unsigned int uint;
typedef unsigned short ushort;
typedef __attribute__((ext_vector_type(8))) short bf16x8;
typedef __attribute__((ext_vector_type(4))) float f32x4;

__device__ __forceinline__ float prelu_f(float x, float a){ return x > 0.f ? x : a*x; }

__device__ __forceinline__ ushort bfr(float x){
  uint u = __float_as_uint(x);
  u = (u + 0x7fffu + ((u>>16)&1u)) >> 16;
  return (ushort)u;
}
__device__ __forceinline__ uint pkbf(float a, float b){
  __hip_bfloat162 h2 = __float22bfloat162_rn(make_float2(a,b));
  union { __hip_bfloat162 h; uint u; } cv; cv.h = h2; return cv.u;
}

// Q pre-scale: (1/sqrt(32)) * log2(e)  -> softmax in exp2 domain
#define QSCALE 0.25505607190037247f
// fixed softmax shift (scores are O(1) << 8; shift cancels exactly in combine)
#define FIXEDM 8.0f

struct MegaParams {
  const float *board,*p0f,*p0u,*p1f,*p1u;
  const float *sp_w1,*sp_b1,*sp_a1,*sp_w2,*sp_b2,*sp_a2,*sp_w3,*sp_b3;
  const float *enc_fac_w,*enc_fac_b,*enc_unit_w,*enc_unit_b,*enc_lin_w,*enc_lin_b;
  const float *ext_fac_w,*ext_fac_b,*ext_unit_w,*ext_unit_b,*ext_lin_w,*ext_lin_b,*ext_ln_g,*ext_ln_b;
  const float *v_w1,*v_b1,*v_a1,*v_w2,*v_b2,*v_a2,*v_lw,*v_lb;
  const float *fo_w1,*fo_b1,*fo_a,*fo_w2,*fo_b2,*ro_w1,*ro_b1,*ro_a,*ro_w2,*ro_b2;
  const int *p0fp,*p0up,*p1fp,*p1up;
  float* out;
  float *sm1,*sm2,*sm;
  ushort *q16,*k16,*vt16;
  float *Hp,*auxl,*seqA,*seqB,*vmap,*vp1,*vp2;
};

// ---------------- conv 3x3 pad-1 (CPT ch/item) ----------------
template<int CIN, int HW, int CPT>
__device__ __forceinline__ void conv_item(int cg_, int pxb, int tid,
    const float* __restrict__ in, const float* __restrict__ w,
    const float* __restrict__ bias, const float* __restrict__ alpha,
    float* __restrict__ out, float* SF){
  float* Ws = SF;
  float* Bs = SF + CPT*CIN*9;
  for (int idx=tid; idx<CPT*CIN*9; idx+=256) Ws[idx] = w[cg_*CPT*CIN*9 + idx];
  if (tid<CPT) Bs[tid] = bias[cg_*CPT+tid];
  __syncthreads();
  int p = pxb*256 + tid;
  int x = p % HW, y = p / HW;
  float a = alpha[0];
  float acc[CPT];
  #pragma unroll
  for (int c=0;c<CPT;++c) acc[c]=Bs[c];
  #pragma unroll 2
  for (int i=0;i<CIN;++i){
    const float* ip = in + i*HW*HW;
    float win[9];
    #pragma unroll
    for (int ky=0;ky<3;++ky){
      int yy = y+ky-1;
      #pragma unroll
      for (int kx=0;kx<3;++kx){
        int xx = x+kx-1;
        bool ok = ((unsigned)yy < (unsigned)HW) && ((unsigned)xx < (unsigned)HW);
        win[ky*3+kx] = ok ? ip[yy*HW+xx] : 0.f;
      }
    }
    #pragma unroll
    for (int c=0;c<CPT;++c){
      const float* wp = &Ws[(c*CIN+i)*9];
      #pragma unroll
      for (int k=0;k<9;++k) acc[c] += win[k]*wp[k];
    }
  }
  #pragma unroll
  for (int c=0;c<CPT;++c)
    out[(cg_*CPT+c)*HW*HW + p] = prelu_f(acc[c], a);
}

// ---------------- scatter ----------------
__device__ __forceinline__ void scatter_item(int e, const MegaParams& P){
  if (e>=SEQ) return;
  const float* feat; const int* pos; int n, ch0, C;
  if (e<2048){ n=e; feat=P.p1u+n*14; pos=P.p1up; ch0=0; C=14; }
  else if (e<2112){ n=e-2048; feat=P.p1f+n*7; pos=P.p1fp; ch0=14; C=7; }
  else if (e<4160){ n=e-2112; feat=P.p0u+n*14; pos=P.p0up; ch0=21; C=14; }
  else { n=e-4160; feat=P.p0f+n*7; pos=P.p0fp; ch0=35; C=7; }
  int off = pos[2*n]*16 + pos[2*n+1];
  for (int c=0;c<C;++c) atomicAdd(&P.vmap[(ch0+c)*256 + off], feat[c]);
}

// ---------------- qkv MM tail (Xs/Ws staged; writes Q/K/VT bf16) ----------------
__device__ __forceinline__ void qkv_mm_tail(int chunk, int m, int h, int tid,
    const float* Xs, const float* Ws, const float* Bs,
    ushort* Q16, ushort* K16, ushort* VT16){
  int og = tid&7, rg = tid>>3;
  const float4* Xs4 = (const float4*)Xs;
  const float4* Ws4 = (const float4*)Ws;
  float acc[2][4];
  #pragma unroll
  for (int k=0;k<4;++k){ float b = Bs[og+8*k]; acc[0][k]=b; acc[1][k]=b; }
  #pragma unroll
  for (int d4=0; d4<10; ++d4){
    float4 xa = Xs4[rg*10+d4];
    float4 xb2 = Xs4[(rg+32)*10+d4];
    #pragma unroll
    for (int k=0;k<4;++k){
      float4 wv = Ws4[(og+8*k)*10+d4];
      acc[0][k] += xa.x*wv.x + xa.y*wv.y + xa.z*wv.z + xa.w*wv.w;
      acc[1][k] += xb2.x*wv.x + xb2.y*wv.y + xb2.z*wv.z + xb2.w*wv.w;
    }
  }
  if (m==0){
    #pragma unroll
    for (int j=0;j<2;++j){
      int r = rg + 32*j;
      ushort* base = Q16 + ((size_t)h*SEQ + chunk*64 + r)*32;
      #pragma unroll
      for (int k=0;k<4;++k) base[og+8*k] = bfr(acc[j][k]*QSCALE);
    }
  } else if (m==1){
    #pragma unroll
    for (int j=0;j<2;++j){
      int r = rg + 32*j;
      ushort* base = K16 + ((size_t)h*SEQ + chunk*64 + r)*32;
      #pragma unroll
      for (int k=0;k<4;++k) base[og+8*k] = bfr(acc[j][k]);
    }
  } else {
    #pragma unroll
    for (int k=0;k<4;++k){
      ushort* base = VT16 + ((size_t)h*32 + og+8*k)*SEQ + chunk*64;
      #pragma unroll
      for (int j=0;j<2;++j) base[rg+32*j] = bfr(acc[j][k]);
    }
  }
}

// ---------------- qkv layer0 (inline gather from sm+feats) ----------------
__device__ __forceinline__ void qkv0_item(int blk, int tid, const MegaParams& P, float* SF){
  float* Xs = SF;           // 64*40
  float* Ws = SF + 2560;    // 32*40
  float* Bs = SF + 3840;    // 32
  int chunk = blk % 66;
  int hm = blk / 66;
  int m = hm >> 1, h = hm & 1;
  int ind, isfac, pl;
  if (chunk==0){ ind=31; isfac=1; pl=0; }
  else if (chunk<=32){ ind=38; isfac=0; pl=0; }
  else if (chunk==33){ ind=31; isfac=1; pl=1; }
  else { ind=38; isfac=0; pl=1; }
  int b0 = h*6 + pl*3 + m;
  const float* w = (isfac? P.enc_fac_w:P.enc_unit_w) + (size_t)b0*32*ind;
  const float* bias = (isfac? P.enc_fac_b:P.enc_unit_b) + b0*32;
  {
    int r = tid>>2, seg = tid&3;
    const float* feat; const int* pos; int nf, n;
    if (chunk==0){ n=r; feat=P.p0f+n*7; pos=P.p0fp; nf=7; }
    else if (chunk<=32){ n=(chunk-1)*64+r; feat=P.p0u+(size_t)n*14; pos=P.p0up; nf=14; }
    else if (chunk==33){ n=r; feat=P.p1f+n*7; pos=P.p1fp; nf=7; }
    else { n=(chunk-34)*64+r; feat=P.p1u+(size_t)n*14; pos=P.p1up; nf=14; }
    int px = pos[2*n], py = pos[2*n+1];
    const float* s = P.sm + px*16 + py;
    #pragma unroll
    for (int j=0;j<10;++j){
      int c = seg*10+j;
      float v;
      if (c<nf) v = feat[c];
      else if (c<ind) v = s[(c-nf)*256];
      else v = 0.f;
      Xs[r*40+c] = v;
    }
    int o = tid>>3, sg = tid&7;
    const float* wr = w + (size_t)o*ind;
    #pragma unroll
    for (int j=0;j<5;++j){ int c = sg*5+j; Ws[o*40+c] = (c<ind) ? wr[c] : 0.f; }
    if (tid<32) Bs[tid]=bias[tid];
  }
  __syncthreads();
  qkv_mm_tail(chunk, m, h, tid, Xs, Ws, Bs, P.q16, P.k16, P.vt16);
}

// ---------------- k-split combine ----------------
__device__ __forceinline__ float combine_row(const float* Hp, const float* auxl, int s, int d){
  int hh = d>>5;
  float den = 0.f, hv = 0.f;
  #pragma unroll
  for (int p=0;p<KSPLIT;++p){
    den += auxl[(size_t)(p*2+hh)*SEQ + s];
    hv  += Hp[(size_t)p*SEQ*64 + (size_t)s*64 + d];
  }
  return hv/den;
}

// ---------------- fused outlin(+LN) prologue -> Xs (64 rows) ----------------
__device__ __forceinline__ void outlin_to_Xs(int chunk, int tid,
    const float* Hp, const float* auxl, const float* lw, const float* lb,
    const float* seqin, const float* g, const float* b, bool LN,
    float* seqwr, float* Xs, float* Ls, float* Hc){
  for (int idx=tid; idx<2048; idx+=256){ int o=idx>>6, d=idx&63; Ls[o*68+d]=lw[idx]; }
  for (int idx=tid; idx<512; idx+=256){ int r=idx>>3, c=32+(idx&7); Xs[r*40+c]=0.f; }
  int o = tid&31, sl = tid>>5;
  for (int rr=0; rr<8; ++rr){
    int srow0 = chunk*64 + rr*8;
    __syncthreads();
    for (int idx=tid; idx<512; idx+=256){
      int s2=idx>>6, d=idx&63;
      Hc[s2*68+d] = combine_row(Hp, auxl, srow0+s2, d);
    }
    __syncthreads();
    int s = srow0 + sl;
    const float4* H4 = (const float4*)&Hc[sl*68];
    const float4* L4 = (const float4*)&Ls[o*68];
    float acc = lb[o] + (LN ? seqin[(size_t)s*32+o] : 0.f);
    #pragma unroll
    for (int d4=0; d4<16; ++d4){
      float4 hv = H4[d4], lv = L4[d4];
      acc += hv.x*lv.x + hv.y*lv.y + hv.z*lv.z + hv.w*lv.w;
    }
    if (LN){
      float sum=acc;
      #pragma unroll
      for (int off=1; off<32; off<<=1) sum += __shfl_xor(sum,off);
      float mu = sum*0.03125f;
      float dv = acc-mu;
      float vs = dv*dv;
      #pragma unroll
      for (int off=1; off<32; off<<=1) vs += __shfl_xor(vs,off);
      float rstd = rsqrtf(vs*0.03125f + 1e-5f);
      acc = dv*rstd*g[o] + b[o];
    }
    Xs[(rr*8+sl)*40 + o] = acc;
    if (seqwr) seqwr[(size_t)s*32+o] = acc;
  }
}

// ---------------- fused outlin + qkv (layers 1,2) ----------------
// SF layout (floats): Xs[2560] Ws[1280] Bs[32] Ls[2176] Hc[544]  = 6592
__device__ __forceinline__ void qkvf_item(int blk, int tid, const MegaParams& P, int layer, float* SF){
  float* Xs = SF;
  float* Ws = SF + 2560;
  float* Bs = SF + 3840;
  float* Ls = SF + 3872;
  float* Hc = SF + 6048;
  int chunk = blk % 66;
  int hm = blk / 66;
  int m = hm >> 1, h = hm & 1;
  // outlin prologue
  if (layer==1){
    outlin_to_Xs(chunk, tid, P.Hp, P.auxl, P.enc_lin_w, P.enc_lin_b,
        nullptr, nullptr, nullptr, false, (hm==0)? P.seqA : nullptr, Xs, Ls, Hc);
  } else {
    outlin_to_Xs(chunk, tid, P.Hp, P.auxl, P.ext_lin_w, P.ext_lin_b,
        P.seqA, P.ext_ln_g, P.ext_ln_b, true, (hm==0)? P.seqB : nullptr, Xs, Ls, Hc);
  }
  // stage W, B
  int isfac = (chunk==0 || chunk==33);
  int pl = (chunk<33) ? 0 : 1;
  int b0 = h*6 + pl*3 + m;
  const float* fw = (layer==1) ? P.ext_fac_w  : P.ext_fac_w+12288;
  const float* fb = (layer==1) ? P.ext_fac_b  : P.ext_fac_b+384;
  const float* uw = (layer==1) ? P.ext_unit_w : P.ext_unit_w+12288;
  const float* ub = (layer==1) ? P.ext_unit_b : P.ext_unit_b+384;
  const float* w = (isfac? fw:uw) + (size_t)b0*32*32;
  const float* bias = (isfac? fb:ub) + b0*32;
  {
    int o = tid>>3, sg = tid&7;
    const float* wr = w + (size_t)o*32;
    #pragma unroll
    for (int j=0;j<5;++j){ int c = sg*5+j; Ws[o*40+c] = (c<32) ? wr[c] : 0.f; }
    if (tid<32) Bs[tid]=bias[tid];
  }
  __syncthreads();
  qkv_mm_tail(chunk, m, h, tid, Xs, Ws, Bs, P.q16, P.k16, P.vt16);
}

// ---------------- MFMA flash attention (LDS dbuf, fixed-shift softmax) ----------------
__device__ __forceinline__ void flash_item(int item, int tid,
    const ushort* Q16, const ushort* K16, const ushort* VT16,
    float* Hpart, float* auxl, ushort* SU){
  ushort* KsB = SU;            // [2][64][40]
  ushort* VTB = SU + 5120;     // [2][32][80]
  ushort* PlB = SU + 10240;    // [4][16][72]
  int qb = item % 66, h = (item/66)&1, ks = item/132;
  int wv = tid>>6, l = tid&63, lq = l&15, g = l>>4;
  const ushort* Qh = Q16 + (size_t)h*SEQ*32;
  const ushort* Kh = K16 + (size_t)h*SEQ*32;
  const ushort* VTh = VT16 + (size_t)h*32*SEQ;

  bf16x8 qf = *(const bf16x8*)(Qh + (size_t)(qb*64 + wv*16 + lq)*32 + g*8);

  int krow = tid>>2, kc8 = (tid&3)*8;
  int vd = tid>>3, vk8 = (tid&7)*8;

  f32x4 o0 = {0.f,0.f,0.f,0.f}, o1 = {0.f,0.f,0.f,0.f};
  float lrow = 0.f;

  int kt0 = ks*KITERS;
  bf16x8 kpre = *(const bf16x8*)(Kh + (size_t)(kt0*64 + krow)*32 + kc8);
  bf16x8 vpre = *(const bf16x8*)(VTh + (size_t)vd*SEQ + kt0*64 + vk8);
  *(bf16x8*)&KsB[0*2560 + krow*40 + kc8] = kpre;
  *(bf16x8*)&VTB[0*2560 + vd*80 + vk8] = vpre;

  for (int it=0; it<KITERS; ++it){
    int pb = it&1;
    if (it+1 < KITERS){
      kpre = *(const bf16x8*)(Kh + (size_t)((kt0+it+1)*64 + krow)*32 + kc8);
      vpre = *(const bf16x8*)(VTh + (size_t)vd*SEQ + (kt0+it+1)*64 + vk8);
    }
    __syncthreads();
    f32x4 z = {0.f,0.f,0.f,0.f};
    f32x4 sT[4];
    #pragma unroll
    for (int m=0;m<4;++m){
      bf16x8 kf = *(const bf16x8*)&KsB[pb*2560 + (16*m+lq)*40 + g*8];
      sT[m] = __builtin_amdgcn_mfma_f32_16x16x32_bf16(kf, qf, z, 0, 0, 0);
    }
    float ts = 0.f;
    #pragma unroll
    for (int m=0;m<4;++m){
      #pragma unroll
      for (int r=0;r<4;++r){ float p = exp2f(sT[m][r]-FIXEDM); sT[m][r]=p; ts+=p; }
    }
    ts += __shfl_xor(ts,16); ts += __shfl_xor(ts,32);
    lrow += ts;
    #pragma unroll
    for (int m=0;m<4;++m){
      uint2 pw; pw.x = pkbf(sT[m][0],sT[m][1]); pw.y = pkbf(sT[m][2],sT[m][3]);
      *(uint2*)&PlB[wv*1152 + lq*72 + 16*m + g*4] = pw;
    }
    #pragma unroll
    for (int s=0;s<2;++s){
      bf16x8 pf = *(const bf16x8*)&PlB[wv*1152 + lq*72 + s*32 + g*8];
      bf16x8 vf0 = *(const bf16x8*)&VTB[pb*2560 + lq*80 + s*32 + g*8];
      bf16x8 vf1 = *(const bf16x8*)&VTB[pb*2560 + (lq+16)*80 + s*32 + g*8];
      o0 = __builtin_amdgcn_mfma_f32_16x16x32_bf16(pf, vf0, o0, 0, 0, 0);
      o1 = __builtin_amdgcn_mfma_f32_16x16x32_bf16(pf, vf1, o1, 0, 0, 0);
    }
    if (it+1 < KITERS){
      *(bf16x8*)&KsB[(pb^1)*2560 + krow*40 + kc8] = kpre;
      *(bf16x8*)&VTB[(pb^1)*2560 + vd*80 + vk8] = vpre;
    }
  }
  int qg0 = qb*64 + wv*16;
  #pragma unroll
  for (int r=0;r<4;++r){
    size_t row = (size_t)ks*SEQ + qg0 + g*4 + r;
    Hpart[row*64 + h*32 + lq]      = o0[r];
    Hpart[row*64 + h*32 + lq + 16] = o1[r];
  }
  if (g==0) auxl[(size_t)(ks*2+h)*SEQ + qg0 + lq] = lrow;
}

// ---------------- value head items ----------------
__device__ __forceinline__ void vconv1_item(int item2, int tid, const MegaParams& P, float* SF){
  float* In = SF;          // 66*96
  float* Wc = SF + 6336;   // 594
  int c = item2>>2, q = item2&3;
  int y0 = q*4;
  const float4* vm4 = (const float4*)P.vmap;
  const float4* sm4 = (const float4*)P.sm;
  float4* In4 = (float4*)In;
  for (int idx4=tid; idx4<1584; idx4+=256){
    int i = idx4/24, rem = idx4 - i*24;
    int r = rem>>2, x4 = rem&3;
    int y = y0 - 1 + r;
    float4 v;
    if ((unsigned)y < 16u) v = (i<42) ? vm4[i*64 + y*4 + x4] : sm4[(i-42)*64 + y*4 + x4];
    else { v.x=v.y=v.z=v.w=0.f; }
    In4[idx4] = v;
  }
  for (int idx=tid; idx<594; idx+=256) Wc[idx] = P.v_w1[c*594 + idx];
  __syncthreads();
  if (tid<64){
    int x = tid & 15, ry = tid >> 4;
    float a = P.v_a1[0];
    float acc = P.v_b1[c];
    for (int i=0;i<66;++i){
      const float* base = &In[i*96 + ry*16];
      const float* wp = &Wc[i*9];
      #pragma unroll
      for (int ky=0;ky<3;++ky){
        const float* row = base + ky*16;
        #pragma unroll
        for (int kx=0;kx<3;++kx){
          int xx = x+kx-1;
          float v = ((unsigned)xx<16u) ? row[xx] : 0.f;
          acc += v*wp[ky*3+kx];
        }
      }
    }
    acc = prelu_f(acc, a);
    float mx = fmaxf(acc, __shfl_xor(acc,1));
    mx = fmaxf(mx, __shfl_xor(mx,16));
    if (((x&1)==0) && ((ry&1)==0))
      P.vp1[c*64 + (q*2 + (ry>>1))*8 + (x>>1)] = mx;
  }
}

__device__ __forceinline__ void vconv2_item(int c, int tid, const MegaParams& P, float* SF){
  float* In = SF;          // 96*64
  float* Ws = SF + 6144;   // 864
  const float4* in4 = (const float4*)P.vp1;
  float4* In4 = (float4*)In;
  for (int idx4=tid; idx4<1536; idx4+=256) In4[idx4] = in4[idx4];
  for (int idx=tid; idx<864; idx+=256) Ws[idx] = P.v_w2[c*864 + idx];
  __syncthreads();
  if (tid<64){
    int x = tid&7, y = tid>>3;
    float acc = P.v_b2[c];
    for (int i=0;i<96;++i){
      const float* base = &In[i*64];
      const float* wp = &Ws[i*9];
      #pragma unroll
      for (int ky=0;ky<3;++ky){
        int yy = y+ky-1;
        #pragma unroll
        for (int kx=0;kx<3;++kx){
          int xx = x+kx-1;
          bool ok = ((unsigned)yy<8u) && ((unsigned)xx<8u);
          float v = ok ? base[yy*8+xx] : 0.f;
          acc += v*wp[ky*3+kx];
        }
      }
    }
    acc = prelu_f(acc, P.v_a2[0]);
    float mx = fmaxf(acc, __shfl_xor(acc,1));
    mx = fmaxf(mx, __shfl_xor(mx,8));
    if (((x&1)==0) && ((y&1)==0))
      P.vp2[c*16 + (y>>1)*4 + (x>>1)] = mx;
  }
}

__device__ __forceinline__ void vfinal_item(int tid, const MegaParams& P, float* SF){
  float* red = SF;
  float s=0.f;
  for (int i=tid;i<2048;i+=256) s += P.vp2[i]*P.v_lw[i];
  red[tid]=s; __syncthreads();
  for (int k=128;k>0;k>>=1){ if (tid<k) red[tid]+=red[tid+k]; __syncthreads(); }
  if (tid==0) P.out[70144] = tanhf(red[0]+P.v_lb[0]);
}

// ---------------- discrete kernels ----------------
__global__ __launch_bounds__(256) void k_conv1z(MegaParams P){
  __shared__ __align__(16) float SF[512];
  if (blockIdx.x < 108)
    conv_item<14,48,4>(blockIdx.x/9, blockIdx.x%9, threadIdx.x, P.board,P.sp_w1,P.sp_b1,P.sp_a1,P.sm1,SF);
  else
    P.vmap[(blockIdx.x-108)*256+threadIdx.x] = 0.f;
}
// conv2 (432) + scatter (17) + sm zero (6)
__global__ __launch_bounds__(256) void k_conv2x(MegaParams P){
  __shared__ __align__(16) float SF[872];
  int b = blockIdx.x;
  if (b < 432)
    conv_item<48,48,2>(b/9, b%9, threadIdx.x, P.sm1,P.sp_w2,P.sp_b2,P.sp_a2,P.sm2,SF);
  else if (b < 449)
    scatter_item((b-432)*256+threadIdx.x, P);
  else {
    int base = (b-449)*1024;
    #pragma unroll
    for (int j=0;j<4;++j) P.sm[base + j*256 + threadIdx.x] = 0.f;
  }
}
// stride-3 conv: 48 blocks = 24 ch x 2 ci-halves, atomicAdd into zeroed sm
__global__ __launch_bounds__(256) void k_convs3(MegaParams P){
  __shared__ __align__(16) float Ws[432];
  int c = blockIdx.x>>1, half = blockIdx.x&1;
  int tid = threadIdx.x;
  for (int idx=tid; idx<432; idx+=256) Ws[idx] = P.sp_w3[c*864 + half*432 + idx];
  __syncthreads();
  int x = tid&15, y = tid>>4;
  float acc = half ? 0.f : P.sp_b3[c];
  const float* ip0 = P.sm2 + (size_t)half*48*2304 + y*144 + x*3;
  #pragma unroll 4
  for (int i=0;i<48;++i){
    const float* ip = ip0 + i*2304;
    float win[9];
    #pragma unroll
    for (int ky=0;ky<3;++ky)
      #pragma unroll
      for (int kx=0;kx<3;++kx) win[ky*3+kx] = ip[ky*48+kx];
    const float* w0 = &Ws[i*9];
    #pragma unroll
    for (int k=0;k<9;++k) acc += win[k]*w0[k];
  }
  atomicAdd(&P.sm[c*256 + y*16 + x], acc);
}
// qkv-enc with inline gather (396) + vconv1 (384)
__global__ __launch_bounds__(256) void k_qkv0_vc1(MegaParams P){
  __shared__ __align__(16) float SF[6930];
  if (blockIdx.x < 396) qkv0_item(blockIdx.x, threadIdx.x, P, SF);
  else vconv1_item(blockIdx.x-396, threadIdx.x, P, SF);
}
// flash (1452) + vconv2 (128) in the first flash dispatch
__global__ __launch_bounds__(256) void k_flash0_vc2(MegaParams P){
  __shared__ __align__(16) char SM[29696];
  if (blockIdx.x < 1452) flash_item(blockIdx.x, threadIdx.x, P.q16,P.k16,P.vt16,P.Hp,P.auxl,(ushort*)SM);
  else vconv2_item(blockIdx.x-1452, threadIdx.x, P, (float*)SM);
}
__global__ __launch_bounds__(256) void k_flash(MegaParams P){
  __shared__ __align__(16) char SM[29696];
  flash_item(blockIdx.x, threadIdx.x, P.q16,P.k16,P.vt16,P.Hp,P.auxl,(ushort*)SM);
}
// fused outlin0+qkv(layer1) (396) + vfinal (1)
__global__ __launch_bounds__(256) void k_qkvf1_vf(MegaParams P){
  __shared__ __align__(16) float SF[6592];
  if (blockIdx.x < 396) qkvf_item(blockIdx.x, threadIdx.x, P, 1, SF);
  else vfinal_item(threadIdx.x, P, SF);
}
// fused outlin1(LN)+qkv(layer2) (396)
__global__ __launch_bounds__(256) void k_qkvf2(MegaParams P){
  __shared__ __align__(16) float SF[6592];
  qkvf_item(blockIdx.x, threadIdx.x, P, 2, SF);
}
// fused final outlin2(LN) + output heads (528)
__global__ __launch_bounds__(256) void k_outlin_head(MegaParams P){
  __shared__ __align__(16) float Ls[2176];
  __shared__ __align__(16) float Hc[544];
  __shared__ float Xr[8*33], Hb[8*33];
  __shared__ float W1f[1024], W1r[1024], W2f[128], W2r[544];
  __shared__ float B1f[32], B1r[32], B2f[4], B2r[17];
  int tid = threadIdx.x;
  const float* lw = P.ext_lin_w + 2048;
  const float* lb = P.ext_lin_b + 32;
  const float* g  = P.ext_ln_g + 32;
  const float* bb = P.ext_ln_b + 32;
  for (int idx=tid; idx<2048; idx+=256){ int o=idx>>6, d=idx&63; Ls[o*68+d]=lw[idx]; }
  for (int i=tid;i<1024;i+=256){ W1f[i]=P.fo_w1[i]; W1r[i]=P.ro_w1[i]; }
  for (int i=tid;i<544;i+=256) W2r[i]=P.ro_w2[i];
  if (tid<128) W2f[tid]=P.fo_w2[tid];
  if (tid<32){ B1f[tid]=P.fo_b1[tid]; B1r[tid]=P.ro_b1[tid]; }
  if (tid<17) B2r[tid]=P.ro_b2[tid];
  if (tid<4)  B2f[tid]=P.fo_b2[tid];
  int s0 = blockIdx.x*8;
  for (int idx=tid; idx<512; idx+=256){
    int s2=idx>>6, d=idx&63;
    Hc[s2*68+d] = combine_row(P.Hp, P.auxl, s0+s2, d);
  }
  __syncthreads();
  int o = tid&31, sl = tid>>5;
  int s = s0 + sl;
  {
    const float4* H4 = (const float4*)&Hc[sl*68];
    const float4* L4 = (const float4*)&Ls[o*68];
    float acc = lb[o] + P.seqB[(size_t)s*32+o];
    #pragma unroll
    for (int d4=0; d4<16; ++d4){
      float4 hv = H4[d4], lv = L4[d4];
      acc += hv.x*lv.x + hv.y*lv.y + hv.z*lv.z + hv.w*lv.w;
    }
    float sum=acc;
    #pragma unroll
    for (int off=1; off<32; off<<=1) sum += __shfl_xor(sum,off);
    float mu = sum*0.03125f;
    float dv = acc-mu;
    float vs = dv*dv;
    #pragma unroll
    for (int off=1; off<32; off<<=1) vs += __shfl_xor(vs,off);
    float rstd = rsqrtf(vs*0.03125f + 1e-5f);
    Xr[sl*33+o] = dv*rstd*g[o] + bb[o];
  }
  __syncthreads();
  bool isfac = (s<64) || (s>=2112 && s<2176);
  float a = isfac ? P.fo_a[0] : P.ro_a[0];
  const float* w1 = isfac ? W1f : W1r;
  const float* b1 = isfac ? B1f : B1r;
  {
    float acc = b1[o];
    const float* xr = &Xr[sl*33];
    #pragma unroll
    for (int i=0;i<32;++i) acc += w1[o*32+i]*xr[i];
    Hb[sl*33+o] = prelu_f(acc, a);
  }
  __syncthreads();
  int od = isfac ? 4 : 17;
  if (o < od){
    const float* w2 = isfac ? W2f : W2r;
    const float* b2 = isfac ? B2f : B2r;
    float acc = b2[o];
    const float* hb = &Hb[sl*33];
    #pragma unroll
    for (int j=0;j<32;++j) acc += w2[o*32+j]*hb[j];
    float* dst;
    if (s<64) dst = P.out + s*4;
    else if (s<2112) dst = P.out + 256 + (size_t)(s-64)*17;
    else if (s<2176) dst = P.out + 35072 + (s-2112)*4;
    else dst = P.out + 35328 + (size_t)(s-2176)*17;
    dst[o] = acc;
  }
}

// ---------------- host ----------------
extern "C" void kernel_launch(void* const* d_in, const int* in_sizes, int n_in,
                              void* d_out, int out_size, void* d_ws, size_t ws_size,
                              hipStream_t stream){
  (void)in_sizes; (void)n_in; (void)out_size; (void)ws_size;
  MegaParams P;
  P.board=(const float*)d_in[0];
  P.p0f=(const float*)d_in[1]; P.p0u=(const float*)d_in[2];
  P.p1f=(const float*)d_in[3]; P.p1u=(const float*)d_in[4];
  P.sp_w1=(const float*)d_in[5]; P.sp_b1=(const float*)d_in[6]; P.sp_a1=(const float*)d_in[7];
  P.sp_w2=(const float*)d_in[8]; P.sp_b2=(const float*)d_in[9]; P.sp_a2=(const float*)d_in[10];
  P.sp_w3=(const float*)d_in[11]; P.sp_b3=(const float*)d_in[12];
  P.enc_fac_w=(const float*)d_in[13]; P.enc_fac_b=(const float*)d_in[14];
  P.enc_unit_w=(const float*)d_in[15]; P.enc_unit_b=(const float*)d_in[16];
  P.enc_lin_w=(const float*)d_in[17]; P.enc_lin_b=(const float*)d_in[18];
  P.ext_fac_w=(const float*)d_in[19]; P.ext_fac_b=(const float*)d_in[20];
  P.ext_unit_w=(const float*)d_in[21]; P.ext_unit_b=(const float*)d_in[22];
  P.ext_lin_w=(const float*)d_in[23]; P.ext_lin_b=(const float*)d_in[24];
  P.ext_ln_g=(const float*)d_in[25]; P.ext_ln_b=(const float*)d_in[26];
  P.v_w1=(const float*)d_in[27]; P.v_b1=(const float*)d_in[28]; P.v_a1=(const float*)d_in[29];
  P.v_w2=(const float*)d_in[30]; P.v_b2=(const float*)d_in[31]; P.v_a2=(const float*)d_in[32];
  P.v_lw=(const float*)d_in[33]; P.v_lb=(const float*)d_in[34];
  P.fo_w1=(const float*)d_in[35]; P.fo_b1=(const float*)d_in[36]; P.fo_a=(const float*)d_in[37];
  P.fo_w2=(const float*)d_in[38]; P.fo_b2=(const float*)d_in[39];
  P.ro_w1=(const float*)d_in[40]; P.ro_b1=(const float*)d_in[41]; P.ro_a=(const float*)d_in[42];
  P.ro_w2=(const float*)d_in[43]; P.ro_b2=(const float*)d_in[44];
  P.p0fp=(const int*)d_in[45]; P.p0up=(const int*)d_in[46];
  P.p1fp=(const int*)d_in[47]; P.p1up=(const int*)d_in[48];
  P.out = (float*)d_out;

  float* W = (float*)d_ws;
  P.sm1 = W;                       // 110592
  P.sm2 = P.sm1 + 110592;          // 221184
  P.sm  = P.sm2 + 221184;          // 6144
  P.q16 = (ushort*)(P.sm + 6144);  // 2*SEQ*32 each
  P.k16 = P.q16 + 2*SEQ*32;
  P.vt16 = P.k16 + 2*SEQ*32;
  P.Hp  = (float*)(P.vt16 + 2*SEQ*32);  // KSPLIT*SEQ*64
  P.auxl = P.Hp + KSPLIT*SEQ*64;        // KSPLIT*2*SEQ
  P.seqA = P.auxl + KSPLIT*2*SEQ;
  P.seqB = P.seqA + SEQ*32;
  P.vmap = P.seqB + SEQ*32;        // 66*256
  P.vp1  = P.vmap + 66*256;        // 96*64
  P.vp2  = P.vp1 + 96*64;          // 128*16

  k_conv1z<<<150,256,0,stream>>>(P);        // conv1 + vmap zero
  k_conv2x<<<455,256,0,stream>>>(P);        // conv2 + scatter + sm zero
  k_convs3<<<48,256,0,stream>>>(P);         // stride-3 conv (atomic halves)
  k_qkv0_vc1<<<780,256,0,stream>>>(P);      // qkv-enc (inline gather) + vconv1
  k_flash0_vc2<<<1580,256,0,stream>>>(P);   // flash-enc + vconv2
  k_qkvf1_vf<<<397,256,0,stream>>>(P);      // fused outlin0 + qkv layer1 + vfinal
  k_flash<<<1452,256,0,stream>>>(P);
  k_qkvf2<<<396,256,0,stream>>>(P);         // fused outlin1(LN) + qkv layer2
  k_flash<<<1452,256,0,stream>>>(P);
  k_outlin_head<<<528,256,0,stream>>>(P);   // fused outlin2(LN) + heads
}

// Round 12
// 324.543 us; speedup vs baseline: 1.1485x; 1.1485x over previous
//
#include <hip/hip_runtime.h>
#include <hip/hip_bf16.h>

#define SEQ 4224
#define KSPLIT 11
#define KITERS 6
typedef unsigned int uint;
typedef unsigned short ushort;
typedef __attribute__((ext_vector_type(8))) short bf16x8;
typedef __attribute__((ext_vector_type(4))) float f32x4;

__device__ __forceinline__ float prelu_f(float x, float a){ return x > 0.f ? x : a*x; }

__device__ __forceinline__ ushort bfr(float x){
  uint u = __float_as_uint(x);
  u = (u + 0x7fffu + ((u>>16)&1u)) >> 16;
  return (ushort)u;
}
__device__ __forceinline__ uint pkbf(float a, float b){
  __hip_bfloat162 h2 = __float22bfloat162_rn(make_float2(a,b));
  union { __hip_bfloat162 h; uint u; } cv; cv.h = h2; return cv.u;
}

// Q pre-scale: (1/sqrt(32)) * log2(e)  -> softmax in exp2 domain
#define QSCALE 0.25505607190037247f
// fixed softmax shift (scores are O(1) << 8; shift cancels exactly in combine)
#define FIXEDM 8.0f

struct MegaParams {
  const float *board,*p0f,*p0u,*p1f,*p1u;
  const float *sp_w1,*sp_b1,*sp_a1,*sp_w2,*sp_b2,*sp_a2,*sp_w3,*sp_b3;
  const float *enc_fac_w,*enc_fac_b,*enc_unit_w,*enc_unit_b,*enc_lin_w,*enc_lin_b;
  const float *ext_fac_w,*ext_fac_b,*ext_unit_w,*ext_unit_b,*ext_lin_w,*ext_lin_b,*ext_ln_g,*ext_ln_b;
  const float *v_w1,*v_b1,*v_a1,*v_w2,*v_b2,*v_a2,*v_lw,*v_lb;
  const float *fo_w1,*fo_b1,*fo_a,*fo_w2,*fo_b2,*ro_w1,*ro_b1,*ro_a,*ro_w2,*ro_b2;
  const int *p0fp,*p0up,*p1fp,*p1up;
  float* out;
  float *sm1,*sm2,*sm;
  ushort *q16,*k16,*vt16;
  float *Hp,*auxl,*seqA,*seqB,*vmap,*vp1,*vp2;
};

// ---------------- conv 3x3 pad-1 (CPT ch/item) ----------------
template<int CIN, int HW, int CPT>
__device__ __forceinline__ void conv_item(int cg_, int pxb, int tid,
    const float* __restrict__ in, const float* __restrict__ w,
    const float* __restrict__ bias, const float* __restrict__ alpha,
    float* __restrict__ out, float* SF){
  float* Ws = SF;
  float* Bs = SF + CPT*CIN*9;
  for (int idx=tid; idx<CPT*CIN*9; idx+=256) Ws[idx] = w[cg_*CPT*CIN*9 + idx];
  if (tid<CPT) Bs[tid] = bias[cg_*CPT+tid];
  __syncthreads();
  int p = pxb*256 + tid;
  int x = p % HW, y = p / HW;
  float a = alpha[0];
  float acc[CPT];
  #pragma unroll
  for (int c=0;c<CPT;++c) acc[c]=Bs[c];
  #pragma unroll 2
  for (int i=0;i<CIN;++i){
    const float* ip = in + i*HW*HW;
    float win[9];
    #pragma unroll
    for (int ky=0;ky<3;++ky){
      int yy = y+ky-1;
      #pragma unroll
      for (int kx=0;kx<3;++kx){
        int xx = x+kx-1;
        bool ok = ((unsigned)yy < (unsigned)HW) && ((unsigned)xx < (unsigned)HW);
        win[ky*3+kx] = ok ? ip[yy*HW+xx] : 0.f;
      }
    }
    #pragma unroll
    for (int c=0;c<CPT;++c){
      const float* wp = &Ws[(c*CIN+i)*9];
      #pragma unroll
      for (int k=0;k<9;++k) acc[c] += win[k]*wp[k];
    }
  }
  #pragma unroll
  for (int c=0;c<CPT;++c)
    out[(cg_*CPT+c)*HW*HW + p] = prelu_f(acc[c], a);
}

// ---------------- scatter ----------------
__device__ __forceinline__ void scatter_item(int e, const MegaParams& P){
  if (e>=SEQ) return;
  const float* feat; const int* pos; int n, ch0, C;
  if (e<2048){ n=e; feat=P.p1u+n*14; pos=P.p1up; ch0=0; C=14; }
  else if (e<2112){ n=e-2048; feat=P.p1f+n*7; pos=P.p1fp; ch0=14; C=7; }
  else if (e<4160){ n=e-2112; feat=P.p0u+n*14; pos=P.p0up; ch0=21; C=14; }
  else { n=e-4160; feat=P.p0f+n*7; pos=P.p0fp; ch0=35; C=7; }
  int off = pos[2*n]*16 + pos[2*n+1];
  for (int c=0;c<C;++c) atomicAdd(&P.vmap[(ch0+c)*256 + off], feat[c]);
}

// ---------------- qkv projection (layer0 does inline gather from sm+feats) ----------------
__device__ __forceinline__ void qkv_item(int blk, int tid, const MegaParams* GP,
    const float* x0, const float* x1, const float* x2, const float* x3,
    int ind_f, int ind_u,
    const float* fw, const float* fb, const float* uw, const float* ub,
    ushort* Q16, ushort* K16, ushort* VT16, float* SF){
  float* Xs = SF;           // 64*40
  float* Ws = SF + 2560;    // 32*40
  float* Bs = SF + 3840;    // 32
  int chunk = blk % 66;
  int hm = blk / 66;
  int m = hm >> 1, h = hm & 1;
  const float* xb=nullptr; int ind, isfac, pl;
  if (chunk==0){ xb=x0; ind=ind_f; isfac=1; pl=0; }
  else if (chunk<=32){ xb = x1 ? x1 + (size_t)(chunk-1)*64*ind_u : nullptr; ind=ind_u; isfac=0; pl=0; }
  else if (chunk==33){ xb=x2; ind=ind_f; isfac=1; pl=1; }
  else { xb = x3 ? x3 + (size_t)(chunk-34)*64*ind_u : nullptr; ind=ind_u; isfac=0; pl=1; }
  int b0 = h*6 + pl*3 + m;
  const float* w = (isfac? fw:uw) + (size_t)b0*32*ind;
  const float* bias = (isfac? fb:ub) + b0*32;
  {
    int r = tid>>2, seg = tid&3;
    if (GP){
      const float* feat; const int* pos; int nf, n;
      if (chunk==0){ n=r; feat=GP->p0f+n*7; pos=GP->p0fp; nf=7; }
      else if (chunk<=32){ n=(chunk-1)*64+r; feat=GP->p0u+(size_t)n*14; pos=GP->p0up; nf=14; }
      else if (chunk==33){ n=r; feat=GP->p1f+n*7; pos=GP->p1fp; nf=7; }
      else { n=(chunk-34)*64+r; feat=GP->p1u+(size_t)n*14; pos=GP->p1up; nf=14; }
      int px = pos[2*n], py = pos[2*n+1];
      const float* s = GP->sm + px*16 + py;
      #pragma unroll
      for (int j=0;j<10;++j){
        int c = seg*10+j;
        float v;
        if (c<nf) v = feat[c];
        else if (c<ind) v = s[(c-nf)*256];
        else v = 0.f;
        Xs[r*40+c] = v;
      }
    } else {
      const float* xr = xb + (size_t)r*ind;
      #pragma unroll
      for (int j=0;j<10;++j){ int c = seg*10+j; Xs[r*40+c] = (c<ind) ? xr[c] : 0.f; }
    }
    int o = tid>>3, sg = tid&7;
    const float* wr = w + (size_t)o*ind;
    #pragma unroll
    for (int j=0;j<5;++j){ int c = sg*5+j; Ws[o*40+c] = (c<ind) ? wr[c] : 0.f; }
    if (tid<32) Bs[tid]=bias[tid];
  }
  __syncthreads();
  int og = tid&7, rg = tid>>3;
  const float4* Xs4 = (const float4*)Xs;
  const float4* Ws4 = (const float4*)Ws;
  float acc[2][4];
  #pragma unroll
  for (int k=0;k<4;++k){ float b = Bs[og+8*k]; acc[0][k]=b; acc[1][k]=b; }
  #pragma unroll
  for (int d4=0; d4<10; ++d4){
    float4 xa = Xs4[rg*10+d4];
    float4 xb2 = Xs4[(rg+32)*10+d4];
    #pragma unroll
    for (int k=0;k<4;++k){
      float4 wv = Ws4[(og+8*k)*10+d4];
      acc[0][k] += xa.x*wv.x + xa.y*wv.y + xa.z*wv.z + xa.w*wv.w;
      acc[1][k] += xb2.x*wv.x + xb2.y*wv.y + xb2.z*wv.z + xb2.w*wv.w;
    }
  }
  if (m==0){
    #pragma unroll
    for (int j=0;j<2;++j){
      int r = rg + 32*j;
      ushort* base = Q16 + ((size_t)h*SEQ + chunk*64 + r)*32;
      #pragma unroll
      for (int k=0;k<4;++k) base[og+8*k] = bfr(acc[j][k]*QSCALE);
    }
  } else if (m==1){
    #pragma unroll
    for (int j=0;j<2;++j){
      int r = rg + 32*j;
      ushort* base = K16 + ((size_t)h*SEQ + chunk*64 + r)*32;
      #pragma unroll
      for (int k=0;k<4;++k) base[og+8*k] = bfr(acc[j][k]);
    }
  } else {
    #pragma unroll
    for (int k=0;k<4;++k){
      ushort* base = VT16 + ((size_t)h*32 + og+8*k)*SEQ + chunk*64;
      #pragma unroll
      for (int j=0;j<2;++j) base[rg+32*j] = bfr(acc[j][k]);
    }
  }
}

// ---------------- MFMA flash attention (LDS dbuf, fixed-shift softmax) ----------------
__device__ __forceinline__ void flash_item(int item, int tid,
    const ushort* Q16, const ushort* K16, const ushort* VT16,
    float* Hpart, float* auxl, ushort* SU){
  ushort* KsB = SU;            // [2][64][40]
  ushort* VTB = SU + 5120;     // [2][32][80]
  ushort* PlB = SU + 10240;    // [4][16][72]
  int qb = item % 66, h = (item/66)&1, ks = item/132;
  int wv = tid>>6, l = tid&63, lq = l&15, g = l>>4;
  const ushort* Qh = Q16 + (size_t)h*SEQ*32;
  const ushort* Kh = K16 + (size_t)h*SEQ*32;
  const ushort* VTh = VT16 + (size_t)h*32*SEQ;

  bf16x8 qf = *(const bf16x8*)(Qh + (size_t)(qb*64 + wv*16 + lq)*32 + g*8);

  int krow = tid>>2, kc8 = (tid&3)*8;
  int vd = tid>>3, vk8 = (tid&7)*8;

  f32x4 o0 = {0.f,0.f,0.f,0.f}, o1 = {0.f,0.f,0.f,0.f};
  float lrow = 0.f;

  int kt0 = ks*KITERS;
  bf16x8 kpre = *(const bf16x8*)(Kh + (size_t)(kt0*64 + krow)*32 + kc8);
  bf16x8 vpre = *(const bf16x8*)(VTh + (size_t)vd*SEQ + kt0*64 + vk8);
  *(bf16x8*)&KsB[0*2560 + krow*40 + kc8] = kpre;
  *(bf16x8*)&VTB[0*2560 + vd*80 + vk8] = vpre;

  for (int it=0; it<KITERS; ++it){
    int pb = it&1;
    if (it+1 < KITERS){
      kpre = *(const bf16x8*)(Kh + (size_t)((kt0+it+1)*64 + krow)*32 + kc8);
      vpre = *(const bf16x8*)(VTh + (size_t)vd*SEQ + (kt0+it+1)*64 + vk8);
    }
    __syncthreads();
    f32x4 z = {0.f,0.f,0.f,0.f};
    f32x4 sT[4];
    #pragma unroll
    for (int m=0;m<4;++m){
      bf16x8 kf = *(const bf16x8*)&KsB[pb*2560 + (16*m+lq)*40 + g*8];
      sT[m] = __builtin_amdgcn_mfma_f32_16x16x32_bf16(kf, qf, z, 0, 0, 0);
    }
    float ts = 0.f;
    #pragma unroll
    for (int m=0;m<4;++m){
      #pragma unroll
      for (int r=0;r<4;++r){ float p = exp2f(sT[m][r]-FIXEDM); sT[m][r]=p; ts+=p; }
    }
    ts += __shfl_xor(ts,16); ts += __shfl_xor(ts,32);
    lrow += ts;
    #pragma unroll
    for (int m=0;m<4;++m){
      uint2 pw; pw.x = pkbf(sT[m][0],sT[m][1]); pw.y = pkbf(sT[m][2],sT[m][3]);
      *(uint2*)&PlB[wv*1152 + lq*72 + 16*m + g*4] = pw;
    }
    #pragma unroll
    for (int s=0;s<2;++s){
      bf16x8 pf = *(const bf16x8*)&PlB[wv*1152 + lq*72 + s*32 + g*8];
      bf16x8 vf0 = *(const bf16x8*)&VTB[pb*2560 + lq*80 + s*32 + g*8];
      bf16x8 vf1 = *(const bf16x8*)&VTB[pb*2560 + (lq+16)*80 + s*32 + g*8];
      o0 = __builtin_amdgcn_mfma_f32_16x16x32_bf16(pf, vf0, o0, 0, 0, 0);
      o1 = __builtin_amdgcn_mfma_f32_16x16x32_bf16(pf, vf1, o1, 0, 0, 0);
    }
    if (it+1 < KITERS){
      *(bf16x8*)&KsB[(pb^1)*2560 + krow*40 + kc8] = kpre;
      *(bf16x8*)&VTB[(pb^1)*2560 + vd*80 + vk8] = vpre;
    }
  }
  int qg0 = qb*64 + wv*16;
  #pragma unroll
  for (int r=0;r<4;++r){
    size_t row = (size_t)ks*SEQ + qg0 + g*4 + r;
    Hpart[row*64 + h*32 + lq]      = o0[r];
    Hpart[row*64 + h*32 + lq + 16] = o1[r];
  }
  if (g==0) auxl[(size_t)(ks*2+h)*SEQ + qg0 + lq] = lrow;
}

// ---------------- outlin (+simple-sum combine, optional residual+LN) ----------------
__device__ __forceinline__ float combine_row(const float* Hp, const float* auxl, int s, int d){
  int hh = d>>5;
  float den = 0.f, hv = 0.f;
  #pragma unroll
  for (int p=0;p<KSPLIT;++p){
    den += auxl[(size_t)(p*2+hh)*SEQ + s];
    hv  += Hp[(size_t)p*SEQ*64 + (size_t)s*64 + d];
  }
  return hv/den;
}

__device__ __forceinline__ void outlin_item(int blk, int tid,
    const float* Hp, const float* auxl, const float* lw, const float* lb,
    const float* seqin, const float* g, const float* b, float* seqout,
    bool LN, float* SF){
  float* Ls = SF;          // 32*68
  float* Hc = SF + 2176;   // 8*68
  int s0 = blk*8;
  for (int idx=tid; idx<2048; idx+=256){ int o=idx>>6, d=idx&63; Ls[o*68+d]=lw[idx]; }
  for (int idx=tid; idx<512; idx+=256){
    int sl = idx>>6, d = idx&63;
    Hc[sl*68+d] = combine_row(Hp, auxl, s0+sl, d);
  }
  __syncthreads();
  int o = tid&31, sl = tid>>5;
  const float4* H4 = (const float4*)&Hc[sl*68];
  const float4* L4 = (const float4*)&Ls[o*68];
  float acc = lb[o] + (LN ? seqin[(s0+sl)*32+o] : 0.f);
  #pragma unroll
  for (int d4=0; d4<16; ++d4){
    float4 hv = H4[d4], lv = L4[d4];
    acc += hv.x*lv.x + hv.y*lv.y + hv.z*lv.z + hv.w*lv.w;
  }
  if (LN){
    float sum=acc;
    #pragma unroll
    for (int off=1; off<32; off<<=1) sum += __shfl_xor(sum,off);
    float mu = sum*0.03125f;
    float dv = acc-mu;
    float vs = dv*dv;
    #pragma unroll
    for (int off=1; off<32; off<<=1) vs += __shfl_xor(vs,off);
    float rstd = rsqrtf(vs*0.03125f + 1e-5f);
    seqout[(s0+sl)*32+o] = dv*rstd*g[o] + b[o];
  } else {
    seqout[(s0+sl)*32+o] = acc;
  }
}

// ---------------- layer dispatch helpers ----------------
__device__ __forceinline__ void qkv_layer(const MegaParams& P, int layer, int blk, int tid, float* SF){
  if (layer==0)
    qkv_item(blk, tid, &P, nullptr,nullptr,nullptr,nullptr, 31,38,
        P.enc_fac_w,P.enc_fac_b,P.enc_unit_w,P.enc_unit_b, P.q16,P.k16,P.vt16, SF);
  else if (layer==1)
    qkv_item(blk, tid, nullptr, P.seqA, P.seqA+64*32, P.seqA+2112*32, P.seqA+2176*32, 32,32,
        P.ext_fac_w,P.ext_fac_b,P.ext_unit_w,P.ext_unit_b, P.q16,P.k16,P.vt16, SF);
  else
    qkv_item(blk, tid, nullptr, P.seqB, P.seqB+64*32, P.seqB+2112*32, P.seqB+2176*32, 32,32,
        P.ext_fac_w+12288,P.ext_fac_b+384,P.ext_unit_w+12288,P.ext_unit_b+384, P.q16,P.k16,P.vt16, SF);
}
__device__ __forceinline__ void outlin_layer(const MegaParams& P, int layer, int blk, int tid, float* SF){
  if (layer==0)
    outlin_item(blk,tid,P.Hp,P.auxl,P.enc_lin_w,P.enc_lin_b,nullptr,nullptr,nullptr,P.seqA,false,SF);
  else
    outlin_item(blk,tid,P.Hp,P.auxl,P.ext_lin_w,P.ext_lin_b,P.seqA,P.ext_ln_g,P.ext_ln_b,P.seqB,true,SF);
}

// ---------------- value head items ----------------
__device__ __forceinline__ void vconv1_item(int item2, int tid, const MegaParams& P, float* SF){
  float* In = SF;          // 66*96
  float* Wc = SF + 6336;   // 594
  int c = item2>>2, q = item2&3;
  int y0 = q*4;
  const float4* vm4 = (const float4*)P.vmap;
  const float4* sm4 = (const float4*)P.sm;
  float4* In4 = (float4*)In;
  for (int idx4=tid; idx4<1584; idx4+=256){
    int i = idx4/24, rem = idx4 - i*24;
    int r = rem>>2, x4 = rem&3;
    int y = y0 - 1 + r;
    float4 v;
    if ((unsigned)y < 16u) v = (i<42) ? vm4[i*64 + y*4 + x4] : sm4[(i-42)*64 + y*4 + x4];
    else { v.x=v.y=v.z=v.w=0.f; }
    In4[idx4] = v;
  }
  for (int idx=tid; idx<594; idx+=256) Wc[idx] = P.v_w1[c*594 + idx];
  __syncthreads();
  if (tid<64){
    int x = tid & 15, ry = tid >> 4;
    float a = P.v_a1[0];
    float acc = P.v_b1[c];
    for (int i=0;i<66;++i){
      const float* base = &In[i*96 + ry*16];
      const float* wp = &Wc[i*9];
      #pragma unroll
      for (int ky=0;ky<3;++ky){
        const float* row = base + ky*16;
        #pragma unroll
        for (int kx=0;kx<3;++kx){
          int xx = x+kx-1;
          float v = ((unsigned)xx<16u) ? row[xx] : 0.f;
          acc += v*wp[ky*3+kx];
        }
      }
    }
    acc = prelu_f(acc, a);
    float mx = fmaxf(acc, __shfl_xor(acc,1));
    mx = fmaxf(mx, __shfl_xor(mx,16));
    if (((x&1)==0) && ((ry&1)==0))
      P.vp1[c*64 + (q*2 + (ry>>1))*8 + (x>>1)] = mx;
  }
}

__device__ __forceinline__ void vconv2_item(int c, int tid, const MegaParams& P, float* SF){
  float* In = SF;          // 96*64
  float* Ws = SF + 6144;   // 864
  const float4* in4 = (const float4*)P.vp1;
  float4* In4 = (float4*)In;
  for (int idx4=tid; idx4<1536; idx4+=256) In4[idx4] = in4[idx4];
  for (int idx=tid; idx<864; idx+=256) Ws[idx] = P.v_w2[c*864 + idx];
  __syncthreads();
  if (tid<64){
    int x = tid&7, y = tid>>3;
    float acc = P.v_b2[c];
    for (int i=0;i<96;++i){
      const float* base = &In[i*64];
      const float* wp = &Ws[i*9];
      #pragma unroll
      for (int ky=0;ky<3;++ky){
        int yy = y+ky-1;
        #pragma unroll
        for (int kx=0;kx<3;++kx){
          int xx = x+kx-1;
          bool ok = ((unsigned)yy<8u) && ((unsigned)xx<8u);
          float v = ok ? base[yy*8+xx] : 0.f;
          acc += v*wp[ky*3+kx];
        }
      }
    }
    acc = prelu_f(acc, P.v_a2[0]);
    float mx = fmaxf(acc, __shfl_xor(acc,1));
    mx = fmaxf(mx, __shfl_xor(mx,8));
    if (((x&1)==0) && ((y&1)==0))
      P.vp2[c*16 + (y>>1)*4 + (x>>1)] = mx;
  }
}

__device__ __forceinline__ void vfinal_item(int tid, const MegaParams& P, float* SF){
  float* red = SF;
  float s=0.f;
  for (int i=tid;i<2048;i+=256) s += P.vp2[i]*P.v_lw[i];
  red[tid]=s; __syncthreads();
  for (int k=128;k>0;k>>=1){ if (tid<k) red[tid]+=red[tid+k]; __syncthreads(); }
  if (tid==0) P.out[70144] = tanhf(red[0]+P.v_lb[0]);
}

// ---------------- discrete kernels ----------------
__global__ __launch_bounds__(256) void k_conv1z(MegaParams P){
  __shared__ __align__(16) float SF[512];
  if (blockIdx.x < 108)
    conv_item<14,48,4>(blockIdx.x/9, blockIdx.x%9, threadIdx.x, P.board,P.sp_w1,P.sp_b1,P.sp_a1,P.sm1,SF);
  else
    P.vmap[(blockIdx.x-108)*256+threadIdx.x] = 0.f;
}
// conv2 (432) + scatter (17) + sm zero (6)
__global__ __launch_bounds__(256) void k_conv2x(MegaParams P){
  __shared__ __align__(16) float SF[872];
  int b = blockIdx.x;
  if (b < 432)
    conv_item<48,48,2>(b/9, b%9, threadIdx.x, P.sm1,P.sp_w2,P.sp_b2,P.sp_a2,P.sm2,SF);
  else if (b < 449)
    scatter_item((b-432)*256+threadIdx.x, P);
  else {
    int base = (b-449)*1024;
    #pragma unroll
    for (int j=0;j<4;++j) P.sm[base + j*256 + threadIdx.x] = 0.f;
  }
}
// stride-3 conv: 48 blocks = 24 ch x 2 ci-halves, atomicAdd into zeroed sm
__global__ __launch_bounds__(256) void k_convs3(MegaParams P){
  __shared__ __align__(16) float Ws[432];
  int c = blockIdx.x>>1, half = blockIdx.x&1;
  int tid = threadIdx.x;
  for (int idx=tid; idx<432; idx+=256) Ws[idx] = P.sp_w3[c*864 + half*432 + idx];
  __syncthreads();
  int x = tid&15, y = tid>>4;
  float acc = half ? 0.f : P.sp_b3[c];
  const float* ip0 = P.sm2 + (size_t)half*48*2304 + y*144 + x*3;
  #pragma unroll 4
  for (int i=0;i<48;++i){
    const float* ip = ip0 + i*2304;
    float win[9];
    #pragma unroll
    for (int ky=0;ky<3;++ky)
      #pragma unroll
      for (int kx=0;kx<3;++kx) win[ky*3+kx] = ip[ky*48+kx];
    const float* w0 = &Ws[i*9];
    #pragma unroll
    for (int k=0;k<9;++k) acc += win[k]*w0[k];
  }
  atomicAdd(&P.sm[c*256 + y*16 + x], acc);
}
// qkv-enc with inline gather (396) + vconv1 (384)
__global__ __launch_bounds__(256) void k_qkv0_vc1(MegaParams P){
  __shared__ __align__(16) float SF[6930];
  if (blockIdx.x < 396) qkv_layer(P, 0, blockIdx.x, threadIdx.x, SF);
  else vconv1_item(blockIdx.x-396, threadIdx.x, P, SF);
}
__global__ __launch_bounds__(256) void k_flash(MegaParams P){
  __shared__ __align__(16) char SM[29696];
  flash_item(blockIdx.x, threadIdx.x, P.q16,P.k16,P.vt16,P.Hp,P.auxl,(ushort*)SM);
}
// outlin-enc (528) + vconv2 (128)
__global__ __launch_bounds__(256) void k_outlin0_vc2(MegaParams P){
  __shared__ __align__(16) float SF[7008];
  if (blockIdx.x < 528) outlin_layer(P, 0, blockIdx.x, threadIdx.x, SF);
  else vconv2_item(blockIdx.x-528, threadIdx.x, P, SF);
}
// qkv layer1 (396) + vfinal (1)
__global__ __launch_bounds__(256) void k_qkv1_vf(MegaParams P){
  __shared__ __align__(16) float SF[3904];
  if (blockIdx.x < 396) qkv_layer(P, 1, blockIdx.x, threadIdx.x, SF);
  else vfinal_item(threadIdx.x, P, SF);
}
__global__ __launch_bounds__(256) void k_qkv(MegaParams P, int layer){
  __shared__ __align__(16) float SF[3904];
  qkv_layer(P, layer, blockIdx.x, threadIdx.x, SF);
}
__global__ __launch_bounds__(256) void k_outlin(MegaParams P, int layer){
  __shared__ __align__(16) float SF[2720];
  outlin_layer(P, layer, blockIdx.x, threadIdx.x, SF);
}
// fused final outlin2(LN) + output heads (528)  [verified in r11]
__global__ __launch_bounds__(256) void k_outlin_head(MegaParams P){
  __shared__ __align__(16) float Ls[2176];
  __shared__ __align__(16) float Hc[544];
  __shared__ float Xr[8*33], Hb[8*33];
  __shared__ float W1f[1024], W1r[1024], W2f[128], W2r[544];
  __shared__ float B1f[32], B1r[32], B2f[4], B2r[17];
  int tid = threadIdx.x;
  const float* lw = P.ext_lin_w + 2048;
  const float* lb = P.ext_lin_b + 32;
  const float* g  = P.ext_ln_g + 32;
  const float* bb = P.ext_ln_b + 32;
  for (int idx=tid; idx<2048; idx+=256){ int o=idx>>6, d=idx&63; Ls[o*68+d]=lw[idx]; }
  for (int i=tid;i<1024;i+=256){ W1f[i]=P.fo_w1[i]; W1r[i]=P.ro_w1[i]; }
  for (int i=tid;i<544;i+=256) W2r[i]=P.ro_w2[i];
  if (tid<128) W2f[tid]=P.fo_w2[tid];
  if (tid<32){ B1f[tid]=P.fo_b1[tid]; B1r[tid]=P.ro_b1[tid]; }
  if (tid<17) B2r[tid]=P.ro_b2[tid];
  if (tid<4)  B2f[tid]=P.fo_b2[tid];
  int s0 = blockIdx.x*8;
  for (int idx=tid; idx<512; idx+=256){
    int s2=idx>>6, d=idx&63;
    Hc[s2*68+d] = combine_row(P.Hp, P.auxl, s0+s2, d);
  }
  __syncthreads();
  int o = tid&31, sl = tid>>5;
  int s = s0 + sl;
  {
    const float4* H4 = (const float4*)&Hc[sl*68];
    const float4* L4 = (const float4*)&Ls[o*68];
    float acc = lb[o] + P.seqB[(size_t)s*32+o];
    #pragma unroll
    for (int d4=0; d4<16; ++d4){
      float4 hv = H4[d4], lv = L4[d4];
      acc += hv.x*lv.x + hv.y*lv.y + hv.z*lv.z + hv.w*lv.w;
    }
    float sum=acc;
    #pragma unroll
    for (int off=1; off<32; off<<=1) sum += __shfl_xor(sum,off);
    float mu = sum*0.03125f;
    float dv = acc-mu;
    float vs = dv*dv;
    #pragma unroll
    for (int off=1; off<32; off<<=1) vs += __shfl_xor(vs,off);
    float rstd = rsqrtf(vs*0.03125f + 1e-5f);
    Xr[sl*33+o] = dv*rstd*g[o] + bb[o];
  }
  __syncthreads();
  bool isfac = (s<64) || (s>=2112 && s<2176);
  float a = isfac ? P.fo_a[0] : P.ro_a[0];
  const float* w1 = isfac ? W1f : W1r;
  const float* b1 = isfac ? B1f : B1r;
  {
    float acc = b1[o];
    const float* xr = &Xr[sl*33];
    #pragma unroll
    for (int i=0;i<32;++i) acc += w1[o*32+i]*xr[i];
    Hb[sl*33+o] = prelu_f(acc, a);
  }
  __syncthreads();
  int od = isfac ? 4 : 17;
  if (o < od){
    const float* w2 = isfac ? W2f : W2r;
    const float* b2 = isfac ? B2f : B2r;
    float acc = b2[o];
    const float* hb = &Hb[sl*33];
    #pragma unroll
    for (int j=0;j<32;++j) acc += w2[o*32+j]*hb[j];
    float* dst;
    if (s<64) dst = P.out + s*4;
    else if (s<2112) dst = P.out + 256 + (size_t)(s-64)*17;
    else if (s<2176) dst = P.out + 35072 + (s-2112)*4;
    else dst = P.out + 35328 + (size_t)(s-2176)*17;
    dst[o] = acc;
  }
}

// ---------------- host ----------------
extern "C" void kernel_launch(void* const* d_in, const int* in_sizes, int n_in,
                              void* d_out, int out_size, void* d_ws, size_t ws_size,
                              hipStream_t stream){
  (void)in_sizes; (void)n_in; (void)out_size; (void)ws_size;
  MegaParams P;
  P.board=(const float*)d_in[0];
  P.p0f=(const float*)d_in[1]; P.p0u=(const float*)d_in[2];
  P.p1f=(const float*)d_in[3]; P.p1u=(const float*)d_in[4];
  P.sp_w1=(const float*)d_in[5]; P.sp_b1=(const float*)d_in[6]; P.sp_a1=(const float*)d_in[7];
  P.sp_w2=(const float*)d_in[8]; P.sp_b2=(const float*)d_in[9]; P.sp_a2=(const float*)d_in[10];
  P.sp_w3=(const float*)d_in[11]; P.sp_b3=(const float*)d_in[12];
  P.enc_fac_w=(const float*)d_in[13]; P.enc_fac_b=(const float*)d_in[14];
  P.enc_unit_w=(const float*)d_in[15]; P.enc_unit_b=(const float*)d_in[16];
  P.enc_lin_w=(const float*)d_in[17]; P.enc_lin_b=(const float*)d_in[18];
  P.ext_fac_w=(const float*)d_in[19]; P.ext_fac_b=(const float*)d_in[20];
  P.ext_unit_w=(const float*)d_in[21]; P.ext_unit_b=(const float*)d_in[22];
  P.ext_lin_w=(const float*)d_in[23]; P.ext_lin_b=(const float*)d_in[24];
  P.ext_ln_g=(const float*)d_in[25]; P.ext_ln_b=(const float*)d_in[26];
  P.v_w1=(const float*)d_in[27]; P.v_b1=(const float*)d_in[28]; P.v_a1=(const float*)d_in[29];
  P.v_w2=(const float*)d_in[30]; P.v_b2=(const float*)d_in[31]; P.v_a2=(const float*)d_in[32];
  P.v_lw=(const float*)d_in[33]; P.v_lb=(const float*)d_in[34];
  P.fo_w1=(const float*)d_in[35]; P.fo_b1=(const float*)d_in[36]; P.fo_a=(const float*)d_in[37];
  P.fo_w2=(const float*)d_in[38]; P.fo_b2=(const float*)d_in[39];
  P.ro_w1=(const float*)d_in[40]; P.ro_b1=(const float*)d_in[41]; P.ro_a=(const float*)d_in[42];
  P.ro_w2=(const float*)d_in[43]; P.ro_b2=(const float*)d_in[44];
  P.p0fp=(const int*)d_in[45]; P.p0up=(const int*)d_in[46];
  P.p1fp=(const int*)d_in[47]; P.p1up=(const int*)d_in[48];
  P.out = (float*)d_out;

  float* W = (float*)d_ws;
  P.sm1 = W;                       // 110592
  P.sm2 = P.sm1 + 110592;          // 221184
  P.sm  = P.sm2 + 221184;          // 6144
  P.q16 = (ushort*)(P.sm + 6144);  // 2*SEQ*32 each
  P.k16 = P.q16 + 2*SEQ*32;
  P.vt16 = P.k16 + 2*SEQ*32;
  P.Hp  = (float*)(P.vt16 + 2*SEQ*32);  // KSPLIT*SEQ*64
  P.auxl = P.Hp + KSPLIT*SEQ*64;        // KSPLIT*2*SEQ
  P.seqA = P.auxl + KSPLIT*2*SEQ;
  P.seqB = P.seqA + SEQ*32;
  P.vmap = P.seqB + SEQ*32;        // 66*256
  P.vp1  = P.vmap + 66*256;        // 96*64
  P.vp2  = P.vp1 + 96*64;          // 128*16

  k_conv1z<<<150,256,0,stream>>>(P);        // conv1 + vmap zero
  k_conv2x<<<455,256,0,stream>>>(P);        // conv2 + scatter + sm zero
  k_convs3<<<48,256,0,stream>>>(P);         // stride-3 conv (atomic halves)
  k_qkv0_vc1<<<780,256,0,stream>>>(P);      // qkv-enc (inline gather) + vconv1
  k_flash<<<1452,256,0,stream>>>(P);
  k_outlin0_vc2<<<656,256,0,stream>>>(P);   // outlin-enc + vconv2
  k_qkv1_vf<<<397,256,0,stream>>>(P);       // qkv layer1 + vfinal
  k_flash<<<1452,256,0,stream>>>(P);
  k_outlin<<<528,256,0,stream>>>(P,1);      // outlin+LN layer1 -> seqB
  k_qkv<<<396,256,0,stream>>>(P,2);
  k_flash<<<1452,256,0,stream>>>(P);
  k_outlin_head<<<528,256,0,stream>>>(P);   // fused outlin2(LN) + heads
}